// Round 7
// baseline (657.273 us; speedup 1.0000x reference)
//
#include <hip/hip_runtime.h>
#include <hip/hip_bf16.h>

#define HIDDEN 128
#define DEPTH 4
#define INTER 512
#define NSTATE 16
#define DT_RANK 8
#define EPS_RMS 1e-5f
#define MTOK 512            // B*T
#define KIN 150528
#define NBLK 512            // tail persistent-kernel grid (2 blocks/CU)
#define BARSTRIDE 1024      // u32 per barrier region (group lines 128B apart)

typedef __attribute__((ext_vector_type(8))) short bf16x8;
typedef __attribute__((ext_vector_type(4))) float f32x4;

__device__ __forceinline__ unsigned short f2bf(float f) {
  unsigned int u = __builtin_bit_cast(unsigned int, f);
  u += 0x7fffu + ((u >> 16) & 1u);
  return (unsigned short)(u >> 16);
}
__device__ __forceinline__ float silu_f(float x) {
  return x / (1.0f + __expf(-x));
}

// ---------------------------------------------------------------------------
// One-shot grid barrier v3: two-level arrival.
// R6 lesson: 256-512 same-address fetch_add RMWs serialize at the coherence
// point (~60cyc each) -> 6-15us/barrier. Fix: 16 groups x 32 blocks; group
// counters on separate 128B lines; 32nd arrival relays to root. Spin RELAXED
// (no per-poll cache ops, R6-proven), one ACQUIRE at exit.
// region layout: root = region[0]; group g counter = region[32 + 32*g].
// ---------------------------------------------------------------------------
__device__ __forceinline__ void gbar(unsigned* region)
{
  __syncthreads();
  if (threadIdx.x == 0) {
    const unsigned g = (unsigned)blockIdx.x >> 5;       // 0..15
    const unsigned old = __hip_atomic_fetch_add(&region[32 + 32 * g], 1u,
                                                __ATOMIC_RELEASE,
                                                __HIP_MEMORY_SCOPE_AGENT);
    if (old == 31u)
      (void)__hip_atomic_fetch_add(&region[0], 1u, __ATOMIC_RELEASE,
                                   __HIP_MEMORY_SCOPE_AGENT);
    while (__hip_atomic_load(&region[0], __ATOMIC_RELAXED,
                             __HIP_MEMORY_SCOPE_AGENT) < 16u)
      __builtin_amdgcn_s_sleep(8);
    (void)__hip_atomic_load(&region[0], __ATOMIC_ACQUIRE,
                            __HIP_MEMORY_SCOPE_AGENT);  // one inv, then go
  }
  __syncthreads();
}

// ---------------------------------------------------------------------------
// zero_part: 4 MB partial buffer zero + 48 KB barrier-region zero.
// ---------------------------------------------------------------------------
__global__ __launch_bounds__(256) void zero_part(float* __restrict__ p,
                                                 unsigned* __restrict__ bar)
{
  const size_t i = (size_t)blockIdx.x * 256 + threadIdx.x;
  ((float4*)p)[i] = (float4){0.f, 0.f, 0.f, 0.f};
  if (blockIdx.x < 12) {
    uint4* b4 = (uint4*)bar;
    b4[(size_t)blockIdx.x * 256 + threadIdx.x] = (uint4){0u, 0u, 0u, 0u};
  }
}

// ---------------------------------------------------------------------------
// Projection GEMM v3 (unchanged, ~85 us): zero-duplication tiling.
// ---------------------------------------------------------------------------
__global__ __launch_bounds__(512) void proj_gemm(
    const float* __restrict__ x, const float* __restrict__ w,
    float* __restrict__ partial)
{
  const int bid = blockIdx.x;          // 0..255
  const int mb = (bid >> 3) & 3;       // 0..3  (M-tile of 128 rows)
  const int kb = (bid & 7) + (bid >> 5) * 8;   // 0..63 (XCD-clustered)
  const int nchunk = 18 + (kb < 24 ? 1 : 0);
  const int c0 = kb * 18 + (kb < 24 ? kb : 24);

  __shared__ char sm[256 * 256];       // 256 rows (x:0-127, w:128-255) x 256 B

  const int tid = threadIdx.x;
  const int lane = tid & 63;
  const int wv = tid >> 6;             // 0..7
  const int wm2 = wv >> 2;             // 0..1  M-half (64 rows)
  const int wn4 = wv & 3;              // 0..3  N-quarter (32 cols)
  const int fr = lane & 15;
  const int kq = lane >> 4;            // 0..3
  const int l31 = lane & 31;
  const int rpar = lane >> 5;          // 0/1

  const float* gptr = (wv < 4)
      ? (x + (size_t)(mb * 128 + wv * 32 + rpar) * KIN + l31 * 4)
      : (w + (size_t)((wv - 4) * 32 + rpar) * KIN + l31 * 4);

  f32x4 acc[4][2];
  #pragma unroll
  for (int mi = 0; mi < 4; ++mi) {
    acc[mi][0] = (f32x4){0.f, 0.f, 0.f, 0.f};
    acc[mi][1] = (f32x4){0.f, 0.f, 0.f, 0.f};
  }

  float4 rv[16];
  {
    const float* base = gptr + (size_t)c0 * 128;
    #pragma unroll
    for (int j = 0; j < 16; ++j)
      rv[j] = *(const float4*)(base + (size_t)(j * 2) * KIN);
  }

  for (int cc = 0; cc < nchunk; ++cc) {
    #pragma unroll
    for (int j = 0; j < 16; ++j) {
      const int r = wv * 32 + j * 2 + rpar;
      const int phys = (l31 * 8) ^ ((r & 7) << 4);
      ushort4 bq = {f2bf(rv[j].x), f2bf(rv[j].y), f2bf(rv[j].z), f2bf(rv[j].w)};
      *(ushort4*)(sm + r * 256 + phys) = bq;
    }
    __syncthreads();
    if (cc + 1 < nchunk) {
      const float* base = gptr + (size_t)(c0 + cc + 1) * 128;
      #pragma unroll
      for (int j = 0; j < 16; ++j)
        rv[j] = *(const float4*)(base + (size_t)(j * 2) * KIN);
    }
    #pragma unroll
    for (int ks = 0; ks < 4; ++ks) {
      const int log = ks * 64 + kq * 16;
      bf16x8 a[4];
      #pragma unroll
      for (int mi = 0; mi < 4; ++mi) {
        const int row = wm2 * 64 + mi * 16 + fr;
        a[mi] = *(const bf16x8*)(sm + row * 256 + (log ^ ((row & 7) << 4)));
      }
      #pragma unroll
      for (int ni = 0; ni < 2; ++ni) {
        const int row = 128 + wn4 * 32 + ni * 16 + fr;
        const bf16x8 b = *(const bf16x8*)(sm + row * 256 + (log ^ ((row & 7) << 4)));
        #pragma unroll
        for (int mi = 0; mi < 4; ++mi)
          acc[mi][ni] = __builtin_amdgcn_mfma_f32_16x16x32_bf16(a[mi], b, acc[mi][ni], 0, 0, 0);
      }
    }
    __syncthreads();
  }
  float* hp = partial + (size_t)(kb & 15) * (MTOK * HIDDEN);
  #pragma unroll
  for (int mi = 0; mi < 4; ++mi)
    #pragma unroll
    for (int ni = 0; ni < 2; ++ni)
      #pragma unroll
      for (int r = 0; r < 4; ++r) {
        const int row = mb * 128 + wm2 * 64 + mi * 16 + kq * 4 + r;
        const int col = wn4 * 32 + ni * 16 + fr;
        atomicAdd(hp + (size_t)row * HIDDEN + col, acc[mi][ni][r]);
      }
}

// ---------------------------------------------------------------------------
// tail_pers v2: 512 blocks (2/CU, 16 waves/CU), ONE TOKEN per block for the
// token-parallel phases; scan takes 2 (b,i)-units per block in parallel.
// Same phase algorithms as R4-R6 (proven), remapped to the finer grain.
// ---------------------------------------------------------------------------
struct TailArgs {
  const float* part; const float* pb;
  float* h; float* hs; float* gate;
  float* uT; float* dtT; float* Bm; float* Cm; float* y;
  float* out;
  const float* ipw; const float* cw; const float* cb;
  const float* xpw; const float* dtw; const float* dtb;
  const float* Alog; const float* Dssm; const float* opw;
  const float* nw; const float* nwf;
  unsigned* bar;
};

__global__ __launch_bounds__(512, 4) void tail_pers(TailArgs A)
{
  const int blk = blockIdx.x;          // 0..511 == token index tk
  const int tid = threadIdx.x;
  const int tk = blk;
  const int b = tk >> 8, tb0 = tk & 255;
  int bk = 0;

  __shared__ __align__(16) char smraw[10752];

  // ---------------- phase A0: h = pb + sum(part) ; rms ; in_proj l=0 -------
  {
    float* hrow = (float*)smraw;             // [128]
    float* hn   = hrow + 128;                // [128]
    if (tid < 128) {
      const int d = tid;
      float hv = A.pb[d];
      #pragma unroll
      for (int s = 0; s < 16; ++s)
        hv += A.part[(size_t)s * (MTOK * HIDDEN) + (size_t)tk * 128 + d];
      A.h[(size_t)tk * 128 + d] = hv;
      hrow[d] = hv;
    }
    __syncthreads();
    if (tid < 64) {
      const float v0 = hrow[tid], v1 = hrow[tid + 64];
      float ss = v0 * v0 + v1 * v1;
      #pragma unroll
      for (int off = 1; off < 64; off <<= 1) ss += __shfl_xor(ss, off);
      const float rr = rsqrtf(ss * (1.0f / 128.0f) + EPS_RMS);
      hn[tid]      = v0 * rr * A.nw[tid];
      hn[tid + 64] = v1 * rr * A.nw[tid + 64];
    }
    __syncthreads();
    #pragma unroll
    for (int j = 0; j < 2; ++j) {
      const int e = tid + j * 512;           // 0..1023
      const float4* hp4 = (const float4*)hn;
      const float4* wp4 = (const float4*)(A.ipw + (size_t)e * 128);
      float a0 = 0.f, a1 = 0.f, a2 = 0.f, a3 = 0.f;
      #pragma unroll
      for (int kk = 0; kk < 32; ++kk) {
        const float4 hvv = hp4[kk], wv4 = wp4[kk];
        a0 += hvv.x * wv4.x; a1 += hvv.y * wv4.y;
        a2 += hvv.z * wv4.z; a3 += hvv.w * wv4.w;
      }
      const float a = (a0 + a1) + (a2 + a3);
      if (e < 512) A.hs[(size_t)tk * 512 + e] = a;
      else         A.gate[(size_t)tk * 512 + (e - 512)] = a;
    }
  }
  gbar(A.bar + (bk++) * BARSTRIDE);

  for (int l = 0; l < DEPTH; ++l) {
    // -------------- phase CONV(l): conv+silu -> uT ; x_proj ; dt ----------
    {
      float* hs4 = (float*)smraw;            // [4][512]
      float* u_l = hs4 + 2048;               // [512]
      float* si  = u_l + 512;                // [40]
      const float* cw  = A.cw  + (size_t)l * 2048;
      const float* cb  = A.cb  + (size_t)l * 512;
      const float* xpw = A.xpw + (size_t)l * 40 * 512;
      const float* dtw = A.dtw + (size_t)l * 512 * 8;
      const float* dtb = A.dtb + (size_t)l * 512;
      #pragma unroll
      for (int j = 0; j < 4; ++j) {          // hs rows tb0-3 .. tb0
        const int o = tid + j * 512;
        const int jj = o >> 9, i = o & 511;
        const int ct = tb0 - 3 + jj;
        hs4[jj * 512 + i] = (ct >= 0) ? A.hs[((size_t)b * 256 + ct) * 512 + i] : 0.f;
      }
      __syncthreads();
      {
        const int i = tid;
        const float4 c4v = *(const float4*)(cw + (size_t)i * 4);
        const float s = cb[i] + c4v.x * hs4[i] + c4v.y * hs4[512 + i]
                              + c4v.z * hs4[1024 + i] + c4v.w * hs4[1536 + i];
        const float uu = silu_f(s);
        u_l[i] = uu;
        A.uT[((size_t)b * 512 + i) * 256 + tb0] = uu;
      }
      __syncthreads();
      if (tid < 320) {                       // x_proj: 8 threads/output
        const int e = tid >> 3, sub = tid & 7;
        const float4* up = (const float4*)(u_l + sub * 64);
        const float4* wp = (const float4*)(xpw + (size_t)e * 512 + sub * 64);
        float a0 = 0.f, a1 = 0.f, a2 = 0.f, a3 = 0.f;
        #pragma unroll
        for (int kk = 0; kk < 16; ++kk) {
          const float4 uv = up[kk], wv4 = wp[kk];
          a0 += uv.x * wv4.x; a1 += uv.y * wv4.y;
          a2 += uv.z * wv4.z; a3 += uv.w * wv4.w;
        }
        float a = (a0 + a1) + (a2 + a3);
        a += __shfl_xor(a, 1); a += __shfl_xor(a, 2); a += __shfl_xor(a, 4);
        if (sub == 0) si[e] = a;
      }
      __syncthreads();
      if (tid < 32) {                        // B, C rows
        if (tid < 16) A.Bm[(size_t)tk * 16 + tid] = si[8 + tid];
        else          A.Cm[(size_t)tk * 16 + (tid - 16)] = si[24 + (tid - 16)];
      }
      {
        const int i = tid;
        float a0 = dtb[i];
        const float* dr = dtw + (size_t)i * 8;
        #pragma unroll
        for (int r = 0; r < 8; ++r) a0 += si[r] * dr[r];
        const float sp = (a0 > 20.f) ? a0 : log1pf(__expf(a0));
        A.dtT[((size_t)b * 512 + i) * 256 + tb0] = sp;
      }
    }
    gbar(A.bar + (bk++) * BARSTRIDE);

    // -------------- phase SCAN(l): 2 (b,i)-units per block, parallel ------
    {
      float* dt_l = (float*)smraw;           // [2][256]
      float* u_l  = dt_l + 512;              // [2][256]
      float* e_l  = u_l + 512;               // [2][272]
      float* P_l  = e_l + 544;               // [2][272]
      const float* Alg = A.Alog + (size_t)l * INTER * NSTATE;
      const float* Dsp = A.Dssm + (size_t)l * INTER;
      const int sub = tid >> 8;              // 0/1
      const int t2 = tid & 255;
      const int c = t2 >> 4, n = t2 & 15;
      const int unit = blk * 2 + sub;        // 0..1023
      const int sb = unit >> 9, si_ = unit & 511;
      dt_l[sub * 256 + t2] = A.dtT[((size_t)sb * 512 + si_) * 256 + t2];
      u_l [sub * 256 + t2] = A.uT [((size_t)sb * 512 + si_) * 256 + t2];
      const float Av = -__expf(Alg[(size_t)si_ * 16 + n]);
      const float Dv = Dsp[si_];
      float Bv[16], Cv[16];
      #pragma unroll
      for (int j = 0; j < 16; ++j) {
        const int t = c * 16 + j;
        Bv[j] = A.Bm[(size_t)sb * 4096 + t * 16 + n];
        Cv[j] = A.Cm[(size_t)sb * 4096 + t * 16 + n];
      }
      __syncthreads();
      float aj[16];
      float s = 0.f, P = 1.f;
      #pragma unroll
      for (int j = 0; j < 16; ++j) {         // pass 1: local scan from 0
        const int t = c * 16 + j;
        const float dtv = dt_l[sub * 256 + t];
        const float a = __expf(Av * dtv);
        aj[j] = a;
        s = a * s + dtv * Bv[j] * u_l[sub * 256 + t];
        P *= a;
      }
      e_l[sub * 272 + c * 17 + n] = s;
      P_l[sub * 272 + c * 17 + n] = P;
      __syncthreads();
      float s0 = 0.f;                        // stitch chunk prefixes
      for (int cc = 0; cc < c; ++cc)
        s0 = P_l[sub * 272 + cc * 17 + n] * s0 + e_l[sub * 272 + cc * 17 + n];
      s = s0;
      #pragma unroll
      for (int j = 0; j < 16; ++j) {         // pass 2: replay with true state
        const int t = c * 16 + j;
        const float dtv = dt_l[sub * 256 + t];
        s = aj[j] * s + dtv * Bv[j] * u_l[sub * 256 + t];
        float p = s * Cv[j];
        p += __shfl_xor(p, 1); p += __shfl_xor(p, 2);
        p += __shfl_xor(p, 4); p += __shfl_xor(p, 8);
        if (n == 0)
          A.y[((size_t)sb * 256 + t) * 512 + si_] = p + u_l[sub * 256 + t] * Dv;
      }
    }
    gbar(A.bar + (bk++) * BARSTRIDE);

    // -------------- phase FA(l): out_proj+res ; rms ; in_proj(l+1)|out ----
    {
      float* y2   = (float*)smraw;           // [512]
      float* hrow = y2 + 512;                // [128]
      float* hn   = hrow + 128;              // [128]
      const float* opw = A.opw + (size_t)l * 128 * 512;
      {
        const float yv = A.y[(size_t)tk * 512 + tid];
        const float g  = A.gate[(size_t)tk * 512 + tid];
        y2[tid] = yv * silu_f(g);
      }
      __syncthreads();
      {
        const int d = tid >> 2, kq = tid & 3;   // 4 threads per d, k-split 128
        const float4* yp = (const float4*)(y2 + kq * 128);
        const float4* wp = (const float4*)(opw + (size_t)d * 512 + kq * 128);
        float a0 = 0.f, a1 = 0.f, a2 = 0.f, a3 = 0.f;
        #pragma unroll
        for (int kk = 0; kk < 32; ++kk) {
          const float4 yv = yp[kk], wv4 = wp[kk];
          a0 += yv.x * wv4.x; a1 += yv.y * wv4.y;
          a2 += yv.z * wv4.z; a3 += yv.w * wv4.w;
        }
        float a = (a0 + a1) + (a2 + a3);
        a += __shfl_xor(a, 1); a += __shfl_xor(a, 2);
        if (kq == 0) {
          const float hv = A.h[(size_t)tk * 128 + d] + a;
          if (l < 3) A.h[(size_t)tk * 128 + d] = hv;
          hrow[d] = hv;
        }
      }
      __syncthreads();
      const float* nwp = (l < 3) ? (A.nw + (size_t)(l + 1) * 128) : A.nwf;
      if (tid < 64) {
        const float v0 = hrow[tid], v1 = hrow[tid + 64];
        float ss = v0 * v0 + v1 * v1;
        #pragma unroll
        for (int off = 1; off < 64; off <<= 1) ss += __shfl_xor(ss, off);
        const float rr = rsqrtf(ss * (1.0f / 128.0f) + EPS_RMS);
        if (l == 3) {
          A.out[(size_t)tk * 128 + tid]      = v0 * rr * nwp[tid];
          A.out[(size_t)tk * 128 + tid + 64] = v1 * rr * nwp[tid + 64];
        } else {
          hn[tid]      = v0 * rr * nwp[tid];
          hn[tid + 64] = v1 * rr * nwp[tid + 64];
        }
      }
      if (l < 3) {
        __syncthreads();
        const float* ipw = A.ipw + (size_t)(l + 1) * 1024 * 128;
        #pragma unroll
        for (int j = 0; j < 2; ++j) {
          const int e = tid + j * 512;
          const float4* hp4 = (const float4*)hn;
          const float4* wp4 = (const float4*)(ipw + (size_t)e * 128);
          float a0 = 0.f, a1 = 0.f, a2 = 0.f, a3 = 0.f;
          #pragma unroll
          for (int kk = 0; kk < 32; ++kk) {
            const float4 hvv = hp4[kk], wv4 = wp4[kk];
            a0 += hvv.x * wv4.x; a1 += hvv.y * wv4.y;
            a2 += hvv.z * wv4.z; a3 += hvv.w * wv4.w;
          }
          const float a = (a0 + a1) + (a2 + a3);
          if (e < 512) A.hs[(size_t)tk * 512 + e] = a;
          else         A.gate[(size_t)tk * 512 + (e - 512)] = a;
        }
      }
    }
    if (l < 3) gbar(A.bar + (bk++) * BARSTRIDE);
  }
}

extern "C" void kernel_launch(void* const* d_in, const int* in_sizes, int n_in,
                              void* d_out, int out_size, void* d_ws, size_t ws_size,
                              hipStream_t stream)
{
  (void)in_sizes; (void)n_in; (void)out_size; (void)ws_size;
  const float* x    = (const float*)d_in[0];
  const float* pw   = (const float*)d_in[1];
  const float* pb   = (const float*)d_in[2];
  const float* ipw  = (const float*)d_in[3];
  const float* cw   = (const float*)d_in[4];
  const float* cb   = (const float*)d_in[5];
  const float* xpw  = (const float*)d_in[6];
  const float* dtw  = (const float*)d_in[7];
  const float* dtb  = (const float*)d_in[8];
  const float* Alog = (const float*)d_in[9];
  const float* Dssm = (const float*)d_in[10];
  const float* opw  = (const float*)d_in[11];
  const float* nw   = (const float*)d_in[12];
  const float* nwf  = (const float*)d_in[13];
  float* out = (float*)d_out;

  float* ws   = (float*)d_ws;                 // ~10.1 MB scratch
  float* part = ws;                           // 16 * 65536 (atomic-accumulated)
  float* h    = part + 16 * 65536;            // 65536
  float* hs   = h + 65536;                    // 262144
  float* gate = hs + 262144;                  // 262144
  float* uT   = gate + 262144;                // 262144
  float* dtT  = uT + 262144;                  // 262144
  float* Bm   = dtT + 262144;                 // 8192
  float* Cm   = Bm + 8192;                    // 8192
  float* y    = Cm + 8192;                    // 262144
  unsigned* bar = (unsigned*)(y + 262144);    // 12 * 1024 u32 = 48 KB

  zero_part<<<dim3(1024), 256, 0, stream>>>(part, bar);
  proj_gemm<<<dim3(256), 512, 0, stream>>>(x, pw, part);

  TailArgs ta;
  ta.part = part; ta.pb = pb;
  ta.h = h; ta.hs = hs; ta.gate = gate;
  ta.uT = uT; ta.dtT = dtT; ta.Bm = Bm; ta.Cm = Cm; ta.y = y;
  ta.out = out;
  ta.ipw = ipw; ta.cw = cw; ta.cb = cb;
  ta.xpw = xpw; ta.dtw = dtw; ta.dtb = dtb;
  ta.Alog = Alog; ta.Dssm = Dssm; ta.opw = opw;
  ta.nw = nw; ta.nwf = nwf;
  ta.bar = bar;

  tail_pers<<<dim3(NBLK), 512, 0, stream>>>(ta);
}